// Round 12
// baseline (265.193 us; speedup 1.0000x reference)
//
#include <hip/hip_runtime.h>
#include <hip/hip_fp16.h>

// StaticGNN: 2-layer GCN. N=50000, E=800000, D=128, fp32 in/out.
// out = relu( D^{-1/2}(A+I)D^{-1/2} (X W_l) + b_l ), x2.
// H fp16; CSR recs int2{src,coef}; counting-sort rank from count's atomic return.
// R12: 8 dispatches. Keeps R11's safe fusions (count+cvtw, single-dispatch
// scan) but reverts the gemm+fill fusion: fill must stay LDS-free so its
// scatter runs at high occupancy (R11's 34KB-LDS fill blocks = +13us).

#define D 128
#define SCAN_B 256
#define WP 136   // LDS pitch (halves) for W^T tile
#define ABI 6    // vmem gathers per agg batch; 4 edges per inst

typedef _Float16 half8 __attribute__((ext_vector_type(8)));
typedef float floatx4 __attribute__((ext_vector_type(4)));

// ---------------- count + cvtw (fused, independent block ranges) ----------------

__global__ void count_cvtw_kernel(const int* __restrict__ dst, int* degInt,
                                  int* __restrict__ rank, int e, int nbe,
                                  const float* __restrict__ W,
                                  __half* __restrict__ WhT) {
    int bid = blockIdx.x;
    int tid = threadIdx.x;
    if (bid < nbe) {
        int i = bid * 256 + tid;
        if (i < e) rank[i] = atomicAdd(&degInt[dst[i]], 1);
    } else {
        // W[l][k][f] fp32 -> WhT[l][f][k] fp16. 128 blocks x 256 = 32768 elems.
        int id = (bid - nbe) * 256 + tid;
        int l = id >> 14;
        int rem = id & 16383;
        int f = rem >> 7;
        int k = rem & 127;
        WhT[id] = __float2half(W[l * 16384 + k * 128 + f]);
    }
}

// ---------------- fused scan: row_ptr + dinv in ONE dispatch ----------------
// Block b redundantly sums deg[0 .. b*256) (L2-hot), then LDS-scans its 256.

__global__ __launch_bounds__(256) void scan_kernel(const int* __restrict__ degInt,
                                                   int* __restrict__ row_ptr,
                                                   float* __restrict__ dinv,
                                                   int n, int nb) {
    __shared__ int sc[256];
    __shared__ int red[4];
    __shared__ int base_s;
    const int tid = threadIdx.x;
    const int bid = blockIdx.x;
    const int start = bid * 256;

    int pre = 0;
    for (int j = tid; j < start; j += 256) pre += degInt[j];
    for (int off = 32; off > 0; off >>= 1) pre += __shfl_down(pre, off, 64);
    if ((tid & 63) == 0) red[tid >> 6] = pre;
    __syncthreads();
    if (tid == 0) base_s = red[0] + red[1] + red[2] + red[3];

    int i = start + tid;
    int c = (i < n) ? degInt[i] : 0;
    sc[tid] = c;
    __syncthreads();
    for (int off = 1; off < 256; off <<= 1) {
        int v = (tid >= off) ? sc[tid - off] : 0;
        __syncthreads();
        sc[tid] += v;
        __syncthreads();
    }
    int base = base_s;
    if (i < n) {
        row_ptr[i] = base + sc[tid] - c;
        dinv[i] = rsqrtf((float)(c + 1));
    }
    if (bid == nb - 1 && tid == 255) row_ptr[n] = base + sc[255];  // = E
}

// ---------------- CSR fill: atomic-free scatter (LDS-free, high occupancy) ----------------

__global__ void fill_kernel(const int* __restrict__ src, const int* __restrict__ dst,
                            const int* __restrict__ rank,
                            const int* __restrict__ row_ptr,
                            const float* __restrict__ dinv,
                            int2* __restrict__ recs, int e) {
    int i = blockIdx.x * blockDim.x + threadIdx.x;
    if (i < e) {
        int d = dst[i];
        int s = src[i];
        int pos = row_ptr[d] + rank[i];
        int2 rec;
        rec.x = s;
        rec.y = __float_as_int(dinv[s] * dinv[d]);
        recs[pos] = rec;
    }
}

// ---------------- MFMA GEMM: Hh[n][128] = X[n][128] @ W (via H^T = W^T X^T) ----------------

__device__ inline void gemm_body(int bid, int tid,
                                 const float* __restrict__ Xf,
                                 const __half* __restrict__ Xh,
                                 const __half* __restrict__ WhT,
                                 __half* __restrict__ Hh, int n, int fromFloat,
                                 _Float16* wlds) {
#pragma unroll
    for (int q = 0; q < 8; ++q) {
        int idx = tid + q * 256;        // 0..2047, each = 8 halves
        int row = idx >> 4;
        int col8 = (idx & 15) * 8;
        const uint2* gsrc = (const uint2*)(WhT + row * 128 + col8);
        uint2 a = gsrc[0];
        uint2 b = gsrc[1];
        uint2* ldst = (uint2*)(wlds + row * WP + col8);
        ldst[0] = a;
        ldst[1] = b;
    }
    __syncthreads();

    const int wave = tid >> 6;
    const int lane = tid & 63;
    const int m = lane & 15;
    const int quad = lane >> 4;

    const int node = bid * 64 + wave * 16 + m;
    const int node_ld = node < n ? node : (n - 1);

    half8 bfr[4];
    if (fromFloat) {
#pragma unroll
        for (int k = 0; k < 4; ++k) {
            const float4* p = (const float4*)(Xf + (size_t)node_ld * 128 + k * 32 + quad * 8);
            float4 lo = p[0];
            float4 hi = p[1];
            half8 h;
            h[0] = (_Float16)lo.x; h[1] = (_Float16)lo.y;
            h[2] = (_Float16)lo.z; h[3] = (_Float16)lo.w;
            h[4] = (_Float16)hi.x; h[5] = (_Float16)hi.y;
            h[6] = (_Float16)hi.z; h[7] = (_Float16)hi.w;
            bfr[k] = h;
        }
    } else {
#pragma unroll
        for (int k = 0; k < 4; ++k) {
            bfr[k] = *(const half8*)(Xh + (size_t)node_ld * 128 + k * 32 + quad * 8);
        }
    }

    floatx4 acc[8];
#pragma unroll
    for (int f = 0; f < 8; ++f) acc[f] = (floatx4){0.f, 0.f, 0.f, 0.f};

#pragma unroll
    for (int f = 0; f < 8; ++f) {
#pragma unroll
        for (int k = 0; k < 4; ++k) {
            half8 a = *(const half8*)(wlds + (f * 16 + m) * WP + k * 32 + quad * 8);
            acc[f] = __builtin_amdgcn_mfma_f32_16x16x32_f16(a, bfr[k], acc[f], 0, 0, 0);
        }
    }

    if (node < n) {
#pragma unroll
        for (int f = 0; f < 8; ++f) {
            __half2 p0 = __floats2half2_rn(acc[f][0], acc[f][1]);
            __half2 p1 = __floats2half2_rn(acc[f][2], acc[f][3]);
            uint2 pk;
            pk.x = *(unsigned int*)&p0;
            pk.y = *(unsigned int*)&p1;
            *(uint2*)(Hh + (size_t)node * 128 + f * 16 + quad * 4) = pk;
        }
    }
}

__global__ __launch_bounds__(256) void gemm_f32in_kernel(const float* __restrict__ Xf,
                                                         const __half* __restrict__ WhT,
                                                         __half* __restrict__ Hh, int n) {
    __shared__ _Float16 wlds[128 * WP];
    gemm_body(blockIdx.x, threadIdx.x, Xf, nullptr, WhT, Hh, n, 1, wlds);
}

__global__ __launch_bounds__(256) void gemm_f16in_kernel(const __half* __restrict__ Xh,
                                                         const __half* __restrict__ WhT,
                                                         __half* __restrict__ Hh, int n) {
    __shared__ _Float16 wlds[128 * WP];
    gemm_body(blockIdx.x, threadIdx.x, nullptr, Xh, WhT, Hh, n, 0, wlds);
}

// ---------------- Aggregation (R10 quarter-wave structure, measured best) ----------------

__device__ inline void unpack8(uint4 u, float* f) {
    union { unsigned int x; __half2 h; } a, b, c, d;
    a.x = u.x; b.x = u.y; c.x = u.z; d.x = u.w;
    float2 f0 = __half22float2(a.h);
    float2 f1 = __half22float2(b.h);
    float2 f2 = __half22float2(c.h);
    float2 f3 = __half22float2(d.h);
    f[0] = f0.x; f[1] = f0.y; f[2] = f1.x; f[3] = f1.y;
    f[4] = f2.x; f[5] = f2.y; f[6] = f3.x; f[7] = f3.y;
}

__global__ __launch_bounds__(256) void agg_kernel(const __half* __restrict__ H,
                                                  const int2* __restrict__ recs,
                                                  const int* __restrict__ row_ptr,
                                                  const float* __restrict__ dinv,
                                                  const float* __restrict__ bias,
                                                  float* __restrict__ YF,
                                                  __half* __restrict__ YH,
                                                  int n, int writeHalf) {
    int wave = threadIdx.x >> 6;
    int lane = threadIdx.x & 63;
    int v = blockIdx.x * 4 + wave;
    if (v >= n) return;

    const int qw = lane >> 4;    // which edge of the quad
    const int fl = lane & 15;    // 8-feature (16B) slice
    const uint4* H16 = (const uint4*)H;  // row = 16 uint4

    float acc[8];
    {
        float di = dinv[v];
        float selfc = (qw == 0) ? di * di : 0.f;
        uint4 hv = H16[(size_t)v * 16 + fl];
        float f[8]; unpack8(hv, f);
#pragma unroll
        for (int t = 0; t < 8; ++t) acc[t] = f[t] * selfc;
    }

    int e0 = row_ptr[v];
    int e1 = row_ptr[v + 1];
    int e = e0;
    for (; e + 4 * ABI <= e1; e += 4 * ABI) {
        int2 r[ABI]; uint4 hu[ABI];
#pragma unroll
        for (int j = 0; j < ABI; ++j) r[j] = recs[e + 4 * j + qw];
#pragma unroll
        for (int j = 0; j < ABI; ++j) hu[j] = H16[(size_t)r[j].x * 16 + fl];
#pragma unroll
        for (int j = 0; j < ABI; ++j) {
            float c = __int_as_float(r[j].y);
            float f[8]; unpack8(hu[j], f);
#pragma unroll
            for (int t = 0; t < 8; ++t) acc[t] = fmaf(f[t], c, acc[t]);
        }
    }
    if (e < e1) {
        int2 r[ABI]; uint4 hu[ABI]; bool act[ABI];
#pragma unroll
        for (int j = 0; j < ABI; ++j) {
            int idx = e + 4 * j + qw;
            act[j] = idx < e1;
            if (act[j]) r[j] = recs[idx];
        }
#pragma unroll
        for (int j = 0; j < ABI; ++j) {
            if (act[j]) hu[j] = H16[(size_t)r[j].x * 16 + fl];
        }
#pragma unroll
        for (int j = 0; j < ABI; ++j) {
            if (act[j]) {
                float c = __int_as_float(r[j].y);
                float f[8]; unpack8(hu[j], f);
#pragma unroll
                for (int t = 0; t < 8; ++t) acc[t] = fmaf(f[t], c, acc[t]);
            }
        }
    }

#pragma unroll
    for (int t = 0; t < 8; ++t) {
        acc[t] += __shfl_xor(acc[t], 16);
        acc[t] += __shfl_xor(acc[t], 32);
    }

    if (qw == 0) {
        const float4* B4 = (const float4*)bias;
        float4 b0 = B4[fl * 2];
        float4 b1 = B4[fl * 2 + 1];
        float o[8];
        o[0] = fmaxf(acc[0] + b0.x, 0.f);
        o[1] = fmaxf(acc[1] + b0.y, 0.f);
        o[2] = fmaxf(acc[2] + b0.z, 0.f);
        o[3] = fmaxf(acc[3] + b0.w, 0.f);
        o[4] = fmaxf(acc[4] + b1.x, 0.f);
        o[5] = fmaxf(acc[5] + b1.y, 0.f);
        o[6] = fmaxf(acc[6] + b1.z, 0.f);
        o[7] = fmaxf(acc[7] + b1.w, 0.f);
        if (writeHalf) {
            __half2 p0 = __floats2half2_rn(o[0], o[1]);
            __half2 p1 = __floats2half2_rn(o[2], o[3]);
            __half2 p2 = __floats2half2_rn(o[4], o[5]);
            __half2 p3 = __floats2half2_rn(o[6], o[7]);
            uint4 pk;
            pk.x = *(unsigned int*)&p0;
            pk.y = *(unsigned int*)&p1;
            pk.z = *(unsigned int*)&p2;
            pk.w = *(unsigned int*)&p3;
            ((uint4*)YH)[(size_t)v * 16 + fl] = pk;
        } else {
            float4* Y4 = (float4*)YF;
            Y4[(size_t)v * 32 + fl * 2]     = make_float4(o[0], o[1], o[2], o[3]);
            Y4[(size_t)v * 32 + fl * 2 + 1] = make_float4(o[4], o[5], o[6], o[7]);
        }
    }
}

// ---------------- launch ----------------

extern "C" void kernel_launch(void* const* d_in, const int* in_sizes, int n_in,
                              void* d_out, int out_size, void* d_ws, size_t ws_size,
                              hipStream_t stream) {
    const float* x = (const float*)d_in[0];
    const int* ei = (const int*)d_in[1];
    const float* W = (const float*)d_in[2];
    const float* b = (const float*)d_in[3];
    float* out = (float*)d_out;

    const int N = in_sizes[0] / D;       // 50000
    const int E = in_sizes[1] / 2;       // 800000

    const int* src = ei;
    const int* dst = ei + E;

    int* wsi = (int*)d_ws;
    float* wsf = (float*)d_ws;
    const size_t o_deg  = 0;                 // N ints (memset 0)
    const size_t o_dinv = o_deg + 50000;     // N floats
    const size_t o_rp   = o_dinv + 50000;    // N+1 ints (pad 50016)
    const size_t o_rank = o_rp + 50016;      // E ints
    const size_t o_rec  = o_rank + 800000;   // E int2 (16B-aligned region)
    const size_t o_h    = o_rec + 1600000;   // N*128 halves = 3.2M words
    const size_t o_wht  = o_h + 3200000;     // 2*128*128 halves = 16384 words
    const size_t o_y1h  = o_wht + 16384;     // N*128 halves

    int* degInt  = wsi + o_deg;
    float* dinv  = wsf + o_dinv;
    int* row_ptr = wsi + o_rp;
    int* rank    = wsi + o_rank;
    int2* recs   = (int2*)(wsi + o_rec);
    __half* h    = (__half*)(wsi + o_h);
    __half* wht  = (__half*)(wsi + o_wht);
    __half* y1h  = (__half*)(wsi + o_y1h);

    const int nb_e = (E + 255) / 256;           // 3125
    const int nb_s = (N + SCAN_B - 1) / SCAN_B; // 196
    const int nb_g = (N + 63) / 64;             // 782
    const int nb_a = (N + 3) / 4;               // 12500

    // D1: zero the degree histogram
    hipMemsetAsync(degInt, 0, (size_t)50000 * sizeof(int), stream);
    // D2: count (+rank) fused with W transpose/convert (independent block range)
    count_cvtw_kernel<<<nb_e + 128, 256, 0, stream>>>(dst, degInt, rank, E, nb_e, W, wht);
    // D3: fused scan -> row_ptr + dinv
    scan_kernel<<<nb_s, SCAN_B, 0, stream>>>(degInt, row_ptr, dinv, N, nb_s);
    // D4: layer-0 GEMM (fp32 input, converts in-kernel)
    gemm_f32in_kernel<<<nb_g, 256, 0, stream>>>(x, wht, h, N);
    // D5: CSR fill (LDS-free, high occupancy)
    fill_kernel<<<nb_e, 256, 0, stream>>>(src, dst, rank, row_ptr, dinv, recs, E);
    // D6: layer-0 aggregation -> y1h (fp16)
    agg_kernel<<<nb_a, 256, 0, stream>>>(h, recs, row_ptr, dinv, b, nullptr, y1h, N, 1);
    // D7: layer-1 GEMM
    gemm_f16in_kernel<<<nb_g, 256, 0, stream>>>(y1h, wht + 16384, h, N);
    // D8: layer-1 aggregation -> out (fp32)
    agg_kernel<<<nb_a, 256, 0, stream>>>(h, recs, row_ptr, dinv, b + D, out, nullptr, N, 0);
}

// Round 13
// 239.811 us; speedup vs baseline: 1.1058x; 1.1058x over previous
//
#include <hip/hip_runtime.h>
#include <hip/hip_fp16.h>

// StaticGNN: 2-layer GCN. N=50000, E=800000, D=128, fp32 in/out.
// out = relu( D^{-1/2}(A+I)D^{-1/2} (X W_l) + b_l ), x2.
// H fp16; CSR recs int2{src,coef}; counting-sort rank from count's atomic return.
// R13 = R10 base (3-dispatch scan, standalone count/cvtw — measured fast)
//       + gemm1+fill fusion (measured -8.7us via R11/R12 A/B).

#define D 128
#define SCAN_B 256
#define WP 136   // LDS pitch (halves) for W^T tile
#define ABI 6    // vmem gathers per agg batch; 4 edges per inst

typedef _Float16 half8 __attribute__((ext_vector_type(8)));
typedef float floatx4 __attribute__((ext_vector_type(4)));

// ---------------- setup kernels (R10 structure) ----------------

__global__ void count_kernel(const int* __restrict__ dst, int* degInt,
                             int* __restrict__ rank, int e) {
    int i = blockIdx.x * blockDim.x + threadIdx.x;
    if (i < e) rank[i] = atomicAdd(&degInt[dst[i]], 1);
}

__global__ __launch_bounds__(SCAN_B) void scanA_kernel(const int* __restrict__ degInt,
                                                       int* __restrict__ partial, int n) {
    __shared__ int red[SCAN_B / 64];
    int tid = threadIdx.x;
    int i = blockIdx.x * SCAN_B + tid;
    int c = (i < n) ? degInt[i] : 0;
    int s = c;
    for (int off = 32; off > 0; off >>= 1) s += __shfl_down(s, off, 64);
    if ((tid & 63) == 0) red[tid >> 6] = s;
    __syncthreads();
    if (tid == 0) {
        int t = 0;
#pragma unroll
        for (int w = 0; w < SCAN_B / 64; ++w) t += red[w];
        partial[blockIdx.x] = t;
    }
}

__global__ __launch_bounds__(256) void scanB_kernel(const int* __restrict__ partial,
                                                    int* __restrict__ blockoff, int nb) {
    __shared__ int sc[256];
    int tid = threadIdx.x;
    int c = (tid < nb) ? partial[tid] : 0;
    sc[tid] = c;
    __syncthreads();
    for (int off = 1; off < 256; off <<= 1) {
        int v = (tid >= off) ? sc[tid - off] : 0;
        __syncthreads();
        sc[tid] += v;
        __syncthreads();
    }
    if (tid <= nb) blockoff[tid] = (tid == 0) ? 0 : sc[tid - 1];
}

__global__ __launch_bounds__(SCAN_B) void scanC_kernel(const int* __restrict__ degInt,
                                                       const int* __restrict__ blockoff,
                                                       int* __restrict__ row_ptr,
                                                       float* __restrict__ dinv,
                                                       int n, int nb) {
    __shared__ int sc[SCAN_B];
    int tid = threadIdx.x;
    int i = blockIdx.x * SCAN_B + tid;
    int c = (i < n) ? degInt[i] : 0;
    sc[tid] = c;
    __syncthreads();
    for (int off = 1; off < SCAN_B; off <<= 1) {
        int v = (tid >= off) ? sc[tid - off] : 0;
        __syncthreads();
        sc[tid] += v;
        __syncthreads();
    }
    if (i < n) {
        int base = blockoff[blockIdx.x] + sc[tid] - c;
        row_ptr[i] = base;
        dinv[i] = rsqrtf((float)(c + 1));
    }
    if (blockIdx.x == 0 && tid == 0) row_ptr[n] = blockoff[nb];
}

// W[l][k][f] fp32 -> WhT[l][f][k] fp16 (transposed per layer).
__global__ __launch_bounds__(256) void cvtw_kernel(const float* __restrict__ W,
                                                   __half* __restrict__ WhT) {
    int id = blockIdx.x * blockDim.x + threadIdx.x;  // < 32768
    int l = id >> 14;
    int rem = id & 16383;
    int f = rem >> 7;
    int k = rem & 127;
    WhT[id] = __float2half(W[l * 16384 + k * 128 + f]);
}

// ---------------- shared device bodies ----------------

__device__ inline void gemm_body(int bid, int tid,
                                 const float* __restrict__ Xf,
                                 const __half* __restrict__ Xh,
                                 const __half* __restrict__ WhT,
                                 __half* __restrict__ Hh, int n, int fromFloat,
                                 _Float16* wlds) {
#pragma unroll
    for (int q = 0; q < 8; ++q) {
        int idx = tid + q * 256;        // 0..2047, each = 8 halves
        int row = idx >> 4;
        int col8 = (idx & 15) * 8;
        const uint2* gsrc = (const uint2*)(WhT + row * 128 + col8);
        uint2 a = gsrc[0];
        uint2 b = gsrc[1];
        uint2* ldst = (uint2*)(wlds + row * WP + col8);
        ldst[0] = a;
        ldst[1] = b;
    }
    __syncthreads();

    const int wave = tid >> 6;
    const int lane = tid & 63;
    const int m = lane & 15;
    const int quad = lane >> 4;

    const int node = bid * 64 + wave * 16 + m;
    const int node_ld = node < n ? node : (n - 1);

    half8 bfr[4];
    if (fromFloat) {
#pragma unroll
        for (int k = 0; k < 4; ++k) {
            const float4* p = (const float4*)(Xf + (size_t)node_ld * 128 + k * 32 + quad * 8);
            float4 lo = p[0];
            float4 hi = p[1];
            half8 h;
            h[0] = (_Float16)lo.x; h[1] = (_Float16)lo.y;
            h[2] = (_Float16)lo.z; h[3] = (_Float16)lo.w;
            h[4] = (_Float16)hi.x; h[5] = (_Float16)hi.y;
            h[6] = (_Float16)hi.z; h[7] = (_Float16)hi.w;
            bfr[k] = h;
        }
    } else {
#pragma unroll
        for (int k = 0; k < 4; ++k) {
            bfr[k] = *(const half8*)(Xh + (size_t)node_ld * 128 + k * 32 + quad * 8);
        }
    }

    floatx4 acc[8];
#pragma unroll
    for (int f = 0; f < 8; ++f) acc[f] = (floatx4){0.f, 0.f, 0.f, 0.f};

#pragma unroll
    for (int f = 0; f < 8; ++f) {
#pragma unroll
        for (int k = 0; k < 4; ++k) {
            half8 a = *(const half8*)(wlds + (f * 16 + m) * WP + k * 32 + quad * 8);
            acc[f] = __builtin_amdgcn_mfma_f32_16x16x32_f16(a, bfr[k], acc[f], 0, 0, 0);
        }
    }

    if (node < n) {
#pragma unroll
        for (int f = 0; f < 8; ++f) {
            __half2 p0 = __floats2half2_rn(acc[f][0], acc[f][1]);
            __half2 p1 = __floats2half2_rn(acc[f][2], acc[f][3]);
            uint2 pk;
            pk.x = *(unsigned int*)&p0;
            pk.y = *(unsigned int*)&p1;
            *(uint2*)(Hh + (size_t)node * 128 + f * 16 + quad * 4) = pk;
        }
    }
}

__device__ inline void fill_body(int i,
                                 const int* __restrict__ src,
                                 const int* __restrict__ dst,
                                 const int* __restrict__ rank,
                                 const int* __restrict__ row_ptr,
                                 const float* __restrict__ dinv,
                                 int2* __restrict__ recs, int e) {
    if (i < e) {
        int d = dst[i];
        int s = src[i];
        int pos = row_ptr[d] + rank[i];
        int2 rec;
        rec.x = s;
        rec.y = __float_as_int(dinv[s] * dinv[d]);
        recs[pos] = rec;
    }
}

// ---------------- fused layer-0 GEMM + CSR fill (measured win: overlap) ----------------

__global__ __launch_bounds__(256) void gemmfill_kernel(const float* __restrict__ Xf,
                                                       const __half* __restrict__ WhT,
                                                       __half* __restrict__ Hh, int n, int nbg,
                                                       const int* __restrict__ src,
                                                       const int* __restrict__ dst,
                                                       const int* __restrict__ rank,
                                                       const int* __restrict__ row_ptr,
                                                       const float* __restrict__ dinv,
                                                       int2* __restrict__ recs, int e) {
    __shared__ _Float16 wlds[128 * WP];
    int bid = blockIdx.x;
    int tid = threadIdx.x;
    if (bid < nbg) {
        gemm_body(bid, tid, Xf, nullptr, WhT, Hh, n, 1, wlds);
    } else {
        fill_body((bid - nbg) * 256 + tid, src, dst, rank, row_ptr, dinv, recs, e);
    }
}

// standalone layer-1 GEMM (fp16 input from agg1)
__global__ __launch_bounds__(256) void gemm_f16in_kernel(const __half* __restrict__ Xh,
                                                         const __half* __restrict__ WhT,
                                                         __half* __restrict__ Hh, int n) {
    __shared__ _Float16 wlds[128 * WP];
    gemm_body(blockIdx.x, threadIdx.x, nullptr, Xh, WhT, Hh, n, 0, wlds);
}

// ---------------- Aggregation (R10 quarter-wave structure, measured best) ----------------

__device__ inline void unpack8(uint4 u, float* f) {
    union { unsigned int x; __half2 h; } a, b, c, d;
    a.x = u.x; b.x = u.y; c.x = u.z; d.x = u.w;
    float2 f0 = __half22float2(a.h);
    float2 f1 = __half22float2(b.h);
    float2 f2 = __half22float2(c.h);
    float2 f3 = __half22float2(d.h);
    f[0] = f0.x; f[1] = f0.y; f[2] = f1.x; f[3] = f1.y;
    f[4] = f2.x; f[5] = f2.y; f[6] = f3.x; f[7] = f3.y;
}

__global__ __launch_bounds__(256) void agg_kernel(const __half* __restrict__ H,
                                                  const int2* __restrict__ recs,
                                                  const int* __restrict__ row_ptr,
                                                  const float* __restrict__ dinv,
                                                  const float* __restrict__ bias,
                                                  float* __restrict__ YF,
                                                  __half* __restrict__ YH,
                                                  int n, int writeHalf) {
    int wave = threadIdx.x >> 6;
    int lane = threadIdx.x & 63;
    int v = blockIdx.x * 4 + wave;
    if (v >= n) return;

    const int qw = lane >> 4;    // which edge of the quad
    const int fl = lane & 15;    // 8-feature (16B) slice
    const uint4* H16 = (const uint4*)H;  // row = 16 uint4

    float acc[8];
    {
        float di = dinv[v];
        float selfc = (qw == 0) ? di * di : 0.f;
        uint4 hv = H16[(size_t)v * 16 + fl];
        float f[8]; unpack8(hv, f);
#pragma unroll
        for (int t = 0; t < 8; ++t) acc[t] = f[t] * selfc;
    }

    int e0 = row_ptr[v];
    int e1 = row_ptr[v + 1];
    int e = e0;
    for (; e + 4 * ABI <= e1; e += 4 * ABI) {
        int2 r[ABI]; uint4 hu[ABI];
#pragma unroll
        for (int j = 0; j < ABI; ++j) r[j] = recs[e + 4 * j + qw];
#pragma unroll
        for (int j = 0; j < ABI; ++j) hu[j] = H16[(size_t)r[j].x * 16 + fl];
#pragma unroll
        for (int j = 0; j < ABI; ++j) {
            float c = __int_as_float(r[j].y);
            float f[8]; unpack8(hu[j], f);
#pragma unroll
            for (int t = 0; t < 8; ++t) acc[t] = fmaf(f[t], c, acc[t]);
        }
    }
    if (e < e1) {
        int2 r[ABI]; uint4 hu[ABI]; bool act[ABI];
#pragma unroll
        for (int j = 0; j < ABI; ++j) {
            int idx = e + 4 * j + qw;
            act[j] = idx < e1;
            if (act[j]) r[j] = recs[idx];
        }
#pragma unroll
        for (int j = 0; j < ABI; ++j) {
            if (act[j]) hu[j] = H16[(size_t)r[j].x * 16 + fl];
        }
#pragma unroll
        for (int j = 0; j < ABI; ++j) {
            if (act[j]) {
                float c = __int_as_float(r[j].y);
                float f[8]; unpack8(hu[j], f);
#pragma unroll
                for (int t = 0; t < 8; ++t) acc[t] = fmaf(f[t], c, acc[t]);
            }
        }
    }

#pragma unroll
    for (int t = 0; t < 8; ++t) {
        acc[t] += __shfl_xor(acc[t], 16);
        acc[t] += __shfl_xor(acc[t], 32);
    }

    if (qw == 0) {
        const float4* B4 = (const float4*)bias;
        float4 b0 = B4[fl * 2];
        float4 b1 = B4[fl * 2 + 1];
        float o[8];
        o[0] = fmaxf(acc[0] + b0.x, 0.f);
        o[1] = fmaxf(acc[1] + b0.y, 0.f);
        o[2] = fmaxf(acc[2] + b0.z, 0.f);
        o[3] = fmaxf(acc[3] + b0.w, 0.f);
        o[4] = fmaxf(acc[4] + b1.x, 0.f);
        o[5] = fmaxf(acc[5] + b1.y, 0.f);
        o[6] = fmaxf(acc[6] + b1.z, 0.f);
        o[7] = fmaxf(acc[7] + b1.w, 0.f);
        if (writeHalf) {
            __half2 p0 = __floats2half2_rn(o[0], o[1]);
            __half2 p1 = __floats2half2_rn(o[2], o[3]);
            __half2 p2 = __floats2half2_rn(o[4], o[5]);
            __half2 p3 = __floats2half2_rn(o[6], o[7]);
            uint4 pk;
            pk.x = *(unsigned int*)&p0;
            pk.y = *(unsigned int*)&p1;
            pk.z = *(unsigned int*)&p2;
            pk.w = *(unsigned int*)&p3;
            ((uint4*)YH)[(size_t)v * 16 + fl] = pk;
        } else {
            float4* Y4 = (float4*)YF;
            Y4[(size_t)v * 32 + fl * 2]     = make_float4(o[0], o[1], o[2], o[3]);
            Y4[(size_t)v * 32 + fl * 2 + 1] = make_float4(o[4], o[5], o[6], o[7]);
        }
    }
}

// ---------------- launch ----------------

extern "C" void kernel_launch(void* const* d_in, const int* in_sizes, int n_in,
                              void* d_out, int out_size, void* d_ws, size_t ws_size,
                              hipStream_t stream) {
    const float* x = (const float*)d_in[0];
    const int* ei = (const int*)d_in[1];
    const float* W = (const float*)d_in[2];
    const float* b = (const float*)d_in[3];
    float* out = (float*)d_out;

    const int N = in_sizes[0] / D;       // 50000
    const int E = in_sizes[1] / 2;       // 800000

    const int* src = ei;
    const int* dst = ei + E;

    int* wsi = (int*)d_ws;
    float* wsf = (float*)d_ws;
    const size_t o_deg  = 0;                 // N ints (memset 0)
    const size_t o_dinv = o_deg + 50000;     // N floats
    const size_t o_rp   = o_dinv + 50000;    // N+1 ints (pad 50016)
    const size_t o_part = o_rp + 50016;      // 256
    const size_t o_boff = o_part + 256;      // 256 -> ends 150528
    const size_t o_rank = o_boff + 256;      // E ints
    const size_t o_rec  = o_rank + 800000;   // E int2 (16B-aligned region)
    const size_t o_h    = o_rec + 1600000;   // N*128 halves = 3.2M words
    const size_t o_wht  = o_h + 3200000;     // 2*128*128 halves = 16384 words
    const size_t o_y1h  = o_wht + 16384;     // N*128 halves

    int* degInt  = wsi + o_deg;
    float* dinv  = wsf + o_dinv;
    int* row_ptr = wsi + o_rp;
    int* partial = wsi + o_part;
    int* blockoff= wsi + o_boff;
    int* rank    = wsi + o_rank;
    int2* recs   = (int2*)(wsi + o_rec);
    __half* h    = (__half*)(wsi + o_h);
    __half* wht  = (__half*)(wsi + o_wht);
    __half* y1h  = (__half*)(wsi + o_y1h);

    const int nb_e = (E + 255) / 256;           // 3125
    const int nb_s = (N + SCAN_B - 1) / SCAN_B; // 196
    const int nb_g = (N + 63) / 64;             // 782
    const int nb_a = (N + 3) / 4;               // 12500

    hipMemsetAsync(degInt, 0, (size_t)50000 * sizeof(int), stream);
    count_kernel<<<nb_e, 256, 0, stream>>>(dst, degInt, rank, E);
    scanA_kernel<<<nb_s, SCAN_B, 0, stream>>>(degInt, partial, N);
    scanB_kernel<<<1, 256, 0, stream>>>(partial, blockoff, nb_s);
    scanC_kernel<<<nb_s, SCAN_B, 0, stream>>>(degInt, blockoff, row_ptr, dinv, N, nb_s);
    cvtw_kernel<<<128, 256, 0, stream>>>(W, wht);
    // fused: layer-0 GEMM (blocks [0,nb_g)) + CSR fill (blocks [nb_g,...))
    gemmfill_kernel<<<nb_g + nb_e, 256, 0, stream>>>(x, wht, h, N, nb_g,
                                                     src, dst, rank, row_ptr, dinv, recs, E);
    agg_kernel<<<nb_a, 256, 0, stream>>>(h, recs, row_ptr, dinv, b, nullptr, y1h, N, 1);
    gemm_f16in_kernel<<<nb_g, 256, 0, stream>>>(y1h, wht + 16384, h, N);
    agg_kernel<<<nb_a, 256, 0, stream>>>(h, recs, row_ptr, dinv, b + D, out, nullptr, N, 0);
}

// Round 14
// 237.638 us; speedup vs baseline: 1.1160x; 1.0091x over previous
//
#include <hip/hip_runtime.h>
#include <hip/hip_fp16.h>

// StaticGNN: 2-layer GCN. N=50000, E=800000, D=128, fp32 in/out.
// out = relu( D^{-1/2}(A+I)D^{-1/2} (X W_l) + b_l ), x2.
// H fp16; CSR recs int2{src,coef}. R14 = R13 + 8-replica degree histogram
// (count atomics contention /8; rank = within-copy rank, fill adds base8)
// + cvtw folded into scanA dispatch. 9 dispatches.

#define D 128
#define SCAN_B 256
#define WP 136   // LDS pitch (halves) for W^T tile
#define ABI 6    // vmem gathers per agg batch; 4 edges per inst

typedef _Float16 half8 __attribute__((ext_vector_type(8)));
typedef float floatx4 __attribute__((ext_vector_type(4)));

// ---------------- setup kernels ----------------

// deg8[8][n] zeroed by memset. Copy c = blockIdx&7. rank = within-copy rank.
__global__ void count_kernel(const int* __restrict__ dst, int* deg8,
                             int* __restrict__ rank, int e, int n) {
    int i = blockIdx.x * blockDim.x + threadIdx.x;
    int c = (blockIdx.x & 7) * n;
    if (i < e) rank[i] = atomicAdd(&deg8[c + dst[i]], 1);
}

// scanA: per-node total degree + per-copy exclusive bases; block sums -> partial.
// cvtw (W fp32 -> W^T fp16) fused as independent block-range tail.
__global__ __launch_bounds__(256) void scanA_cvtw_kernel(const int* __restrict__ deg8,
                                                         int* __restrict__ degT,
                                                         int* __restrict__ base8,
                                                         int* __restrict__ partial,
                                                         int n, int nbs,
                                                         const float* __restrict__ W,
                                                         __half* __restrict__ WhT) {
    __shared__ int red[4];
    int tid = threadIdx.x;
    int bid = blockIdx.x;
    if (bid < nbs) {
        int i = bid * 256 + tid;
        int tot = 0;
        if (i < n) {
            int run = 0;
#pragma unroll
            for (int c = 0; c < 8; ++c) {
                base8[c * n + i] = run;
                run += deg8[c * n + i];
            }
            degT[i] = run;
            tot = run;
        }
        for (int off = 32; off > 0; off >>= 1) tot += __shfl_down(tot, off, 64);
        if ((tid & 63) == 0) red[tid >> 6] = tot;
        __syncthreads();
        if (tid == 0) partial[bid] = red[0] + red[1] + red[2] + red[3];
    } else {
        // W[l][k][f] -> WhT[l][f][k]; 128 blocks x 256 threads = 32768 elems
        int id = (bid - nbs) * 256 + tid;
        int l = id >> 14;
        int rem = id & 16383;
        int f = rem >> 7;
        int k = rem & 127;
        WhT[id] = __float2half(W[l * 16384 + k * 128 + f]);
    }
}

__global__ __launch_bounds__(256) void scanB_kernel(const int* __restrict__ partial,
                                                    int* __restrict__ blockoff, int nb) {
    __shared__ int sc[256];
    int tid = threadIdx.x;
    int c = (tid < nb) ? partial[tid] : 0;
    sc[tid] = c;
    __syncthreads();
    for (int off = 1; off < 256; off <<= 1) {
        int v = (tid >= off) ? sc[tid - off] : 0;
        __syncthreads();
        sc[tid] += v;
        __syncthreads();
    }
    if (tid <= nb) blockoff[tid] = (tid == 0) ? 0 : sc[tid - 1];
}

__global__ __launch_bounds__(SCAN_B) void scanC_kernel(const int* __restrict__ degT,
                                                       const int* __restrict__ blockoff,
                                                       int* __restrict__ row_ptr,
                                                       float* __restrict__ dinv,
                                                       int n, int nb) {
    __shared__ int sc[SCAN_B];
    int tid = threadIdx.x;
    int i = blockIdx.x * SCAN_B + tid;
    int c = (i < n) ? degT[i] : 0;
    sc[tid] = c;
    __syncthreads();
    for (int off = 1; off < SCAN_B; off <<= 1) {
        int v = (tid >= off) ? sc[tid - off] : 0;
        __syncthreads();
        sc[tid] += v;
        __syncthreads();
    }
    if (i < n) {
        int base = blockoff[blockIdx.x] + sc[tid] - c;
        row_ptr[i] = base;
        dinv[i] = rsqrtf((float)(c + 1));
    }
    if (blockIdx.x == 0 && tid == 0) row_ptr[n] = blockoff[nb];
}

// ---------------- shared device bodies ----------------

__device__ inline void gemm_body(int bid, int tid,
                                 const float* __restrict__ Xf,
                                 const __half* __restrict__ Xh,
                                 const __half* __restrict__ WhT,
                                 __half* __restrict__ Hh, int n, int fromFloat,
                                 _Float16* wlds) {
#pragma unroll
    for (int q = 0; q < 8; ++q) {
        int idx = tid + q * 256;        // 0..2047, each = 8 halves
        int row = idx >> 4;
        int col8 = (idx & 15) * 8;
        const uint2* gsrc = (const uint2*)(WhT + row * 128 + col8);
        uint2 a = gsrc[0];
        uint2 b = gsrc[1];
        uint2* ldst = (uint2*)(wlds + row * WP + col8);
        ldst[0] = a;
        ldst[1] = b;
    }
    __syncthreads();

    const int wave = tid >> 6;
    const int lane = tid & 63;
    const int m = lane & 15;
    const int quad = lane >> 4;

    const int node = bid * 64 + wave * 16 + m;
    const int node_ld = node < n ? node : (n - 1);

    half8 bfr[4];
    if (fromFloat) {
#pragma unroll
        for (int k = 0; k < 4; ++k) {
            const float4* p = (const float4*)(Xf + (size_t)node_ld * 128 + k * 32 + quad * 8);
            float4 lo = p[0];
            float4 hi = p[1];
            half8 h;
            h[0] = (_Float16)lo.x; h[1] = (_Float16)lo.y;
            h[2] = (_Float16)lo.z; h[3] = (_Float16)lo.w;
            h[4] = (_Float16)hi.x; h[5] = (_Float16)hi.y;
            h[6] = (_Float16)hi.z; h[7] = (_Float16)hi.w;
            bfr[k] = h;
        }
    } else {
#pragma unroll
        for (int k = 0; k < 4; ++k) {
            bfr[k] = *(const half8*)(Xh + (size_t)node_ld * 128 + k * 32 + quad * 8);
        }
    }

    floatx4 acc[8];
#pragma unroll
    for (int f = 0; f < 8; ++f) acc[f] = (floatx4){0.f, 0.f, 0.f, 0.f};

#pragma unroll
    for (int f = 0; f < 8; ++f) {
#pragma unroll
        for (int k = 0; k < 4; ++k) {
            half8 a = *(const half8*)(wlds + (f * 16 + m) * WP + k * 32 + quad * 8);
            acc[f] = __builtin_amdgcn_mfma_f32_16x16x32_f16(a, bfr[k], acc[f], 0, 0, 0);
        }
    }

    if (node < n) {
#pragma unroll
        for (int f = 0; f < 8; ++f) {
            __half2 p0 = __floats2half2_rn(acc[f][0], acc[f][1]);
            __half2 p1 = __floats2half2_rn(acc[f][2], acc[f][3]);
            uint2 pk;
            pk.x = *(unsigned int*)&p0;
            pk.y = *(unsigned int*)&p1;
            *(uint2*)(Hh + (size_t)node * 128 + f * 16 + quad * 4) = pk;
        }
    }
}

__device__ inline void fill_body(int i,
                                 const int* __restrict__ src,
                                 const int* __restrict__ dst,
                                 const int* __restrict__ rank,
                                 const int* __restrict__ row_ptr,
                                 const int* __restrict__ base8,
                                 const float* __restrict__ dinv,
                                 int2* __restrict__ recs, int e, int n) {
    if (i < e) {
        int d = dst[i];
        int s = src[i];
        int c = (i >> 8) & 7;   // copy used by count (blockIdx&7, blockDim=256)
        int pos = row_ptr[d] + base8[c * n + d] + rank[i];
        int2 rec;
        rec.x = s;
        rec.y = __float_as_int(dinv[s] * dinv[d]);
        recs[pos] = rec;
    }
}

// ---------------- fused layer-0 GEMM + CSR fill (measured win: overlap) ----------------

__global__ __launch_bounds__(256) void gemmfill_kernel(const float* __restrict__ Xf,
                                                       const __half* __restrict__ WhT,
                                                       __half* __restrict__ Hh, int n, int nbg,
                                                       const int* __restrict__ src,
                                                       const int* __restrict__ dst,
                                                       const int* __restrict__ rank,
                                                       const int* __restrict__ row_ptr,
                                                       const int* __restrict__ base8,
                                                       const float* __restrict__ dinv,
                                                       int2* __restrict__ recs, int e) {
    __shared__ _Float16 wlds[128 * WP];
    int bid = blockIdx.x;
    int tid = threadIdx.x;
    if (bid < nbg) {
        gemm_body(bid, tid, Xf, nullptr, WhT, Hh, n, 1, wlds);
    } else {
        fill_body((bid - nbg) * 256 + tid, src, dst, rank, row_ptr, base8, dinv, recs, e, n);
    }
}

__global__ __launch_bounds__(256) void gemm_f16in_kernel(const __half* __restrict__ Xh,
                                                         const __half* __restrict__ WhT,
                                                         __half* __restrict__ Hh, int n) {
    __shared__ _Float16 wlds[128 * WP];
    gemm_body(blockIdx.x, threadIdx.x, nullptr, Xh, WhT, Hh, n, 0, wlds);
}

// ---------------- Aggregation (R10 quarter-wave structure, measured best) ----------------

__device__ inline void unpack8(uint4 u, float* f) {
    union { unsigned int x; __half2 h; } a, b, c, d;
    a.x = u.x; b.x = u.y; c.x = u.z; d.x = u.w;
    float2 f0 = __half22float2(a.h);
    float2 f1 = __half22float2(b.h);
    float2 f2 = __half22float2(c.h);
    float2 f3 = __half22float2(d.h);
    f[0] = f0.x; f[1] = f0.y; f[2] = f1.x; f[3] = f1.y;
    f[4] = f2.x; f[5] = f2.y; f[6] = f3.x; f[7] = f3.y;
}

__global__ __launch_bounds__(256) void agg_kernel(const __half* __restrict__ H,
                                                  const int2* __restrict__ recs,
                                                  const int* __restrict__ row_ptr,
                                                  const float* __restrict__ dinv,
                                                  const float* __restrict__ bias,
                                                  float* __restrict__ YF,
                                                  __half* __restrict__ YH,
                                                  int n, int writeHalf) {
    int wave = threadIdx.x >> 6;
    int lane = threadIdx.x & 63;
    int v = blockIdx.x * 4 + wave;
    if (v >= n) return;

    const int qw = lane >> 4;    // which edge of the quad
    const int fl = lane & 15;    // 8-feature (16B) slice
    const uint4* H16 = (const uint4*)H;  // row = 16 uint4

    float acc[8];
    {
        float di = dinv[v];
        float selfc = (qw == 0) ? di * di : 0.f;
        uint4 hv = H16[(size_t)v * 16 + fl];
        float f[8]; unpack8(hv, f);
#pragma unroll
        for (int t = 0; t < 8; ++t) acc[t] = f[t] * selfc;
    }

    int e0 = row_ptr[v];
    int e1 = row_ptr[v + 1];
    int e = e0;
    for (; e + 4 * ABI <= e1; e += 4 * ABI) {
        int2 r[ABI]; uint4 hu[ABI];
#pragma unroll
        for (int j = 0; j < ABI; ++j) r[j] = recs[e + 4 * j + qw];
#pragma unroll
        for (int j = 0; j < ABI; ++j) hu[j] = H16[(size_t)r[j].x * 16 + fl];
#pragma unroll
        for (int j = 0; j < ABI; ++j) {
            float c = __int_as_float(r[j].y);
            float f[8]; unpack8(hu[j], f);
#pragma unroll
            for (int t = 0; t < 8; ++t) acc[t] = fmaf(f[t], c, acc[t]);
        }
    }
    if (e < e1) {
        int2 r[ABI]; uint4 hu[ABI]; bool act[ABI];
#pragma unroll
        for (int j = 0; j < ABI; ++j) {
            int idx = e + 4 * j + qw;
            act[j] = idx < e1;
            if (act[j]) r[j] = recs[idx];
        }
#pragma unroll
        for (int j = 0; j < ABI; ++j) {
            if (act[j]) hu[j] = H16[(size_t)r[j].x * 16 + fl];
        }
#pragma unroll
        for (int j = 0; j < ABI; ++j) {
            if (act[j]) {
                float c = __int_as_float(r[j].y);
                float f[8]; unpack8(hu[j], f);
#pragma unroll
                for (int t = 0; t < 8; ++t) acc[t] = fmaf(f[t], c, acc[t]);
            }
        }
    }

#pragma unroll
    for (int t = 0; t < 8; ++t) {
        acc[t] += __shfl_xor(acc[t], 16);
        acc[t] += __shfl_xor(acc[t], 32);
    }

    if (qw == 0) {
        const float4* B4 = (const float4*)bias;
        float4 b0 = B4[fl * 2];
        float4 b1 = B4[fl * 2 + 1];
        float o[8];
        o[0] = fmaxf(acc[0] + b0.x, 0.f);
        o[1] = fmaxf(acc[1] + b0.y, 0.f);
        o[2] = fmaxf(acc[2] + b0.z, 0.f);
        o[3] = fmaxf(acc[3] + b0.w, 0.f);
        o[4] = fmaxf(acc[4] + b1.x, 0.f);
        o[5] = fmaxf(acc[5] + b1.y, 0.f);
        o[6] = fmaxf(acc[6] + b1.z, 0.f);
        o[7] = fmaxf(acc[7] + b1.w, 0.f);
        if (writeHalf) {
            __half2 p0 = __floats2half2_rn(o[0], o[1]);
            __half2 p1 = __floats2half2_rn(o[2], o[3]);
            __half2 p2 = __floats2half2_rn(o[4], o[5]);
            __half2 p3 = __floats2half2_rn(o[6], o[7]);
            uint4 pk;
            pk.x = *(unsigned int*)&p0;
            pk.y = *(unsigned int*)&p1;
            pk.z = *(unsigned int*)&p2;
            pk.w = *(unsigned int*)&p3;
            ((uint4*)YH)[(size_t)v * 16 + fl] = pk;
        } else {
            float4* Y4 = (float4*)YF;
            Y4[(size_t)v * 32 + fl * 2]     = make_float4(o[0], o[1], o[2], o[3]);
            Y4[(size_t)v * 32 + fl * 2 + 1] = make_float4(o[4], o[5], o[6], o[7]);
        }
    }
}

// ---------------- launch ----------------

extern "C" void kernel_launch(void* const* d_in, const int* in_sizes, int n_in,
                              void* d_out, int out_size, void* d_ws, size_t ws_size,
                              hipStream_t stream) {
    const float* x = (const float*)d_in[0];
    const int* ei = (const int*)d_in[1];
    const float* W = (const float*)d_in[2];
    const float* b = (const float*)d_in[3];
    float* out = (float*)d_out;

    const int N = in_sizes[0] / D;       // 50000
    const int E = in_sizes[1] / 2;       // 800000

    const int* src = ei;
    const int* dst = ei + E;

    int* wsi = (int*)d_ws;
    float* wsf = (float*)d_ws;
    const size_t o_deg8 = 0;                 // 8*N ints (memset 0)
    const size_t o_degT = o_deg8 + 400000;   // N ints
    const size_t o_dinv = o_degT + 50000;    // N floats
    const size_t o_rp   = o_dinv + 50000;    // N+1 ints (pad 50016)
    const size_t o_part = o_rp + 50016;      // 256
    const size_t o_boff = o_part + 256;      // 256
    const size_t o_b8   = o_boff + 256;      // 8*N ints
    const size_t o_rank = o_b8 + 400000;     // E ints
    const size_t o_rec  = o_rank + 800000;   // E int2 (region 16B-aligned)
    const size_t o_h    = o_rec + 1600000;   // N*128 halves = 3.2M words
    const size_t o_wht  = o_h + 3200000;     // 2*128*128 halves = 16384 words
    const size_t o_y1h  = o_wht + 16384;     // N*128 halves

    int* deg8    = wsi + o_deg8;
    int* degT    = wsi + o_degT;
    float* dinv  = wsf + o_dinv;
    int* row_ptr = wsi + o_rp;
    int* partial = wsi + o_part;
    int* blockoff= wsi + o_boff;
    int* base8   = wsi + o_b8;
    int* rank    = wsi + o_rank;
    int2* recs   = (int2*)(wsi + o_rec);
    __half* h    = (__half*)(wsi + o_h);
    __half* wht  = (__half*)(wsi + o_wht);
    __half* y1h  = (__half*)(wsi + o_y1h);

    const int nb_e = (E + 255) / 256;           // 3125
    const int nb_s = (N + SCAN_B - 1) / SCAN_B; // 196
    const int nb_g = (N + 63) / 64;             // 782
    const int nb_a = (N + 3) / 4;               // 12500

    hipMemsetAsync(deg8, 0, (size_t)8 * 50000 * sizeof(int), stream);
    count_kernel<<<nb_e, 256, 0, stream>>>(dst, deg8, rank, E, N);
    scanA_cvtw_kernel<<<nb_s + 128, 256, 0, stream>>>(deg8, degT, base8, partial,
                                                      N, nb_s, W, wht);
    scanB_kernel<<<1, 256, 0, stream>>>(partial, blockoff, nb_s);
    scanC_kernel<<<nb_s, SCAN_B, 0, stream>>>(degT, blockoff, row_ptr, dinv, N, nb_s);
    // fused: layer-0 GEMM (blocks [0,nb_g)) + CSR fill (blocks [nb_g,...))
    gemmfill_kernel<<<nb_g + nb_e, 256, 0, stream>>>(x, wht, h, N, nb_g,
                                                     src, dst, rank, row_ptr, base8,
                                                     dinv, recs, E);
    agg_kernel<<<nb_a, 256, 0, stream>>>(h, recs, row_ptr, dinv, b, nullptr, y1h, N, 1);
    gemm_f16in_kernel<<<nb_g, 256, 0, stream>>>(y1h, wht + 16384, h, N);
    agg_kernel<<<nb_a, 256, 0, stream>>>(h, recs, row_ptr, dinv, b + D, out, nullptr, N, 0);
}